// Round 1
// baseline (152.094 us; speedup 1.0000x reference)
//
#include <hip/hip_runtime.h>
#include <math.h>

// Problem constants (fixed by reference)
#define BB 8
#define CC 512
#define NH 8
#define DK 64
#define NN 1024          // Hs*Ws = 32*32
#define MROWS (BB * NN)  // 8192
#define INNER 512        // NH*DK
#define SCALE 0.125f     // 1/sqrt(64), folded into Q epilogue (exact)

// NOTE (R8-R11 lesson): single-kernel fusion via grid-wide barriers is dead on
// this harness. cg::grid().sync computes correctly (R9 direct call) but
// hipLaunchCooperativeKernel breaks graph capture; hand-rolled barriers with
// __threadfence / __threadfence_system both leave stale per-XCD L2 lines
// (R10: 1.71e-2, R11: 1.67e-2 partial corruption). 4-kernel pipeline it is.

typedef __attribute__((ext_vector_type(8))) short bf16x8;
typedef __attribute__((ext_vector_type(4))) float floatx4;

__device__ inline short f2bf(float f) {  // RNE
    union { float f; unsigned u; } un;
    un.f = f;
    unsigned r = un.u + 0x7fffu + ((un.u >> 16) & 1u);
    return (short)(r >> 16);
}

__device__ inline short f2bf_rhu(float f) {  // round-half-up: 2 VALU
    union { float f; unsigned u; } un;
    un.f = f;
    return (short)((un.u + 0x8000u) >> 16);
}

#define GLD_LDS(gptr, lptr)                                                  \
    __builtin_amdgcn_global_load_lds(                                        \
        (const __attribute__((address_space(1))) void*)(gptr),               \
        (__attribute__((address_space(3))) void*)(lptr), 16, 0, 0)

// ---------------------------------------------------------------------------
// Kernel 1: fused prep — transpose x [B,C,N]->[B,N,C] bf16 (blocks 0..4095),
// weight cvt Wq|Wkv -> wqkvb [1536][512], Wp -> wpb, bias concat (>=4096).
// ---------------------------------------------------------------------------
__global__ __launch_bounds__(256) void prep_kernel(
    const float* __restrict__ x, const float* __restrict__ Wq,
    const float* __restrict__ Wkv, const float* __restrict__ Wp,
    const float* __restrict__ bq, const float* __restrict__ bkv,
    short* __restrict__ xtb, short* __restrict__ wqkvb,
    short* __restrict__ wpb, float* __restrict__ bqkv) {
    __shared__ float tile[32][33];
    const int bid = blockIdx.x;
    if (bid < 4096) {
        const int n0 = (bid & 31) * 32;
        const int c0 = ((bid >> 5) & 15) * 32;
        const int b = bid >> 9;
        const int tx = threadIdx.x & 31;
        const int ty = threadIdx.x >> 5;
        const float* xb = x + (size_t)b * CC * NN;
        short* xo = xtb + (size_t)b * NN * CC;
        for (int i = ty; i < 32; i += 8)
            tile[i][tx] = xb[(size_t)(c0 + i) * NN + n0 + tx];
        __syncthreads();
        for (int i = ty; i < 32; i += 8)
            xo[(size_t)(n0 + i) * CC + c0 + tx] = f2bf(tile[tx][i]);
    } else {
        const int i = (bid - 4096) * 1024 + threadIdx.x * 4;
        if (i < 786432) {
            float4 v = (i < 262144) ? *(const float4*)&Wq[i]
                                    : *(const float4*)&Wkv[i - 262144];
            wqkvb[i + 0] = f2bf(v.x);
            wqkvb[i + 1] = f2bf(v.y);
            wqkvb[i + 2] = f2bf(v.z);
            wqkvb[i + 3] = f2bf(v.w);
        } else if (i < 1048576) {
            const int j = i - 786432;
            float4 v = *(const float4*)&Wp[j];
            wpb[j + 0] = f2bf(v.x);
            wpb[j + 1] = f2bf(v.y);
            wpb[j + 2] = f2bf(v.z);
            wpb[j + 3] = f2bf(v.w);
        } else {
            const int j = i - 1048576;
            if (j < 1536) {
                float4 v = (j < 512) ? *(const float4*)&bq[j]
                                     : *(const float4*)&bkv[j - 512];
                *(float4*)&bqkv[j] = v;
            }
        }
    }
}

// ---------------------------------------------------------------------------
// Kernel 2: bf16 MFMA GEMM  out = A @ W^T + bias
//   128 x BN tile, BK=32, 256 thr (4 waves), double-buffered K-loop.
//   MODE 0: fp32 row-major to outf (final projection, Nw=512)
//   MODE 1: fused QKV (Nw=1536). ALL outputs go through an LDS C-repack for
//     fully-coalesced stores (R7 proved V; R12 extends to Q/K):
//       V  (bn0>=1024): Cs[jn][m] -> vt rows, 16B frags along n (256B spans)
//       Q/K (bn0<1024): Cs[m][jn] -> q/k rows, 16B frags along d (128B spans)
//     (old Q/K scatter was 2B stores in 32B runs at 128B stride: ~2x write amp)
// ---------------------------------------------------------------------------
template <int MODE, int BN>
__global__ __launch_bounds__(256) void gemm_mfma_kernel(
    const short* __restrict__ A, const short* __restrict__ W,
    const float* __restrict__ bias, float* __restrict__ outf,
    short* __restrict__ outq, short* __restrict__ outk,
    short* __restrict__ outv) {
    constexpr int K = 512;
    constexpr int WCOLS = BN / 64;
    constexpr int WROWS = 4 / WCOLS;
    constexpr int WRSPAN = 128 / WROWS;
    constexpr int RT = WRSPAN / 16;
    constexpr int ABUF = 128 * 32;
    constexpr int BBUF = BN * 32;
    constexpr int STAGE_EL = 2 * ABUF + 2 * BBUF;
    constexpr int CS_EL = (MODE == 1) ? 128 * 132 : 0;  // repack tile
    constexpr int SMEM_EL = (CS_EL > STAGE_EL) ? CS_EL : STAGE_EL;
    __shared__ short smem[SMEM_EL];
    short* As = smem;
    short* Bs = smem + 2 * ABUF;

    const int t = threadIdx.x;
    const int wave = t >> 6;
    const int lane = t & 63;
    const int col = lane & 15;
    const int quad = lane >> 4;
    const int wr = wave / WCOLS;
    const int wc = wave % WCOLS;

    const int bm0 = blockIdx.x * 128;
    const int bn0 = blockIdx.y * BN;

    floatx4 acc[RT][4];
#pragma unroll
    for (int i = 0; i < RT; i++)
#pragma unroll
        for (int j = 0; j < 4; j++) acc[i][j] = (floatx4){0.f, 0.f, 0.f, 0.f};

    const int kpE = (lane & 3) * 8;
    const int rA = wave * 32 + (lane >> 2);
    const short* Ag = A + (size_t)(bm0 + rA) * K + kpE;
    const int rB = wave * (BN / 4) + (lane >> 2);
    const short* Wg = W + (size_t)(bn0 + rB) * K + kpE;
    const int aOff = wave * 1024;
    const int bOff = wave * (BN / 4) * 32;

#define GSTAGE(K0, BUF)                                                       \
    do {                                                                      \
        GLD_LDS(Ag + (K0), As + (BUF)*ABUF + aOff);                           \
        GLD_LDS(Ag + 16 * K + (K0), As + (BUF)*ABUF + aOff + 512);            \
        if constexpr (BN == 128) {                                            \
            GLD_LDS(Wg + (K0), Bs + (BUF)*BBUF + bOff);                       \
            GLD_LDS(Wg + 16 * K + (K0), Bs + (BUF)*BBUF + bOff + 512);        \
        } else {                                                              \
            GLD_LDS(Wg + (K0), Bs + (BUF)*BBUF + bOff);                       \
        }                                                                     \
    } while (0)

    GSTAGE(0, 0);

#pragma unroll
    for (int it = 0; it < 16; it++) {
        const int buf = it & 1;
        __syncthreads();
        if (it < 15) GSTAGE((it + 1) * 32, buf ^ 1);

        const short* A_ = As + buf * ABUF;
        const short* B_ = Bs + buf * BBUF;
        bf16x8 aF[RT], bF[4];
#pragma unroll
        for (int rt = 0; rt < RT; rt++)
            aF[rt] =
                *(const bf16x8*)&A_[(wr * WRSPAN + rt * 16 + col) * 32 + quad * 8];
#pragma unroll
        for (int ct = 0; ct < 4; ct++)
            bF[ct] = *(const bf16x8*)&B_[(wc * 64 + ct * 16 + col) * 32 + quad * 8];
#pragma unroll
        for (int rt = 0; rt < RT; rt++)
#pragma unroll
            for (int ct = 0; ct < 4; ct++)
                acc[rt][ct] = __builtin_amdgcn_mfma_f32_16x16x32_bf16(
                    aF[rt], bF[ct], acc[rt][ct], 0, 0, 0);
    }
#undef GSTAGE

    if (MODE == 1) {
        short* Cs = smem;  // reuses staging area; stride 132 breaks pow-2 banks
        const bool isV = (bn0 >= 1024);
        const bool isQ = (bn0 < 512);
        __syncthreads();  // all waves done reading As/Bs
        if (isV) {
            // V: Cs[jn][m], short4 along m (values identical to R8 path)
#pragma unroll
            for (int rt = 0; rt < RT; rt++) {
#pragma unroll
                for (int ct = 0; ct < 4; ct++) {
                    const int jn_l = wc * 64 + ct * 16 + col;
                    const float bsv = bias[bn0 + jn_l];
                    const int m_l = wr * WRSPAN + rt * 16 + quad * 4;
                    short4 v4;
                    v4.x = f2bf(acc[rt][ct][0] + bsv);
                    v4.y = f2bf(acc[rt][ct][1] + bsv);
                    v4.z = f2bf(acc[rt][ct][2] + bsv);
                    v4.w = f2bf(acc[rt][ct][3] + bsv);
                    *(short4*)&Cs[jn_l * 132 + m_l] = v4;
                }
            }
        } else {
            // Q/K: Cs[m][jn] (jn contiguous -> 16B frags along d at store)
#pragma unroll
            for (int rt = 0; rt < RT; rt++) {
#pragma unroll
                for (int ct = 0; ct < 4; ct++) {
                    const int jn_l = wc * 64 + ct * 16 + col;
                    const float bsv = bias[bn0 + jn_l];
#pragma unroll
                    for (int r = 0; r < 4; r++) {
                        const int m_l = wr * WRSPAN + rt * 16 + quad * 4 + r;
                        const float val = acc[rt][ct][r] + bsv;
                        Cs[m_l * 132 + jn_l] =
                            isQ ? f2bf(val * SCALE) : f2bf(val);
                    }
                }
            }
        }
        __syncthreads();
        const int b = bm0 >> 10;
        const int nbase = bm0 & 1023;
        if (isV) {
#pragma unroll
            for (int p = 0; p < 8; p++) {
                const int cid = p * 256 + t;
                const int jn_l = cid >> 4;
                const int m0 = (cid & 15) * 8;
                bf16x8 frag = *(const bf16x8*)&Cs[jn_l * 132 + m0];
                const int jn_g = bn0 + jn_l;
                const int h = (jn_g >> 6) & 7;
                const int d = jn_g & 63;
                *(bf16x8*)&outv[(((size_t)(b * NH + h)) * DK + d) * NN + nbase +
                                m0] = frag;
            }
        } else {
            short* dst = isQ ? outq : outk;
#pragma unroll
            for (int p = 0; p < 8; p++) {
                const int cid = p * 256 + t;
                const int m_l = cid >> 4;
                const int jn0 = (cid & 15) * 8;
                bf16x8 frag = *(const bf16x8*)&Cs[m_l * 132 + jn0];
                const int jn_g = bn0 + jn0;
                const int h = (jn_g >> 6) & 7;
                const int d = jn_g & 63;
                *(bf16x8*)&dst[(((size_t)(b * NH + h)) * NN + nbase + m_l) * DK +
                               d] = frag;
            }
        }
        return;
    }

    // MODE 0: fp32 row-major store (already coalesced per 16-lane col group)
#pragma unroll
    for (int rt = 0; rt < RT; rt++) {
#pragma unroll
        for (int ct = 0; ct < 4; ct++) {
            const int jn = bn0 + wc * 64 + ct * 16 + col;
            const float bsv = bias[jn];
#pragma unroll
            for (int r = 0; r < 4; r++) {
                const int m = bm0 + wr * WRSPAN + rt * 16 + quad * 4 + r;
                outf[(size_t)m * 512 + jn] = acc[rt][ct][r] + bsv;
            }
        }
    }
}

// ---------------------------------------------------------------------------
// Kernel 3: MFMA flash attention, bf16, no online max (scores bounded ~1.3).
// R13: attn was LDS-read-BW-bound (each wave re-read the full K/V tile:
// 160 KB LDS traffic per block-iter for 128 MFMAs ≈ 8x the MFMA demand).
// Restructure: 4 waves x 32 q-rows (2 row-frags per wave) so every K/V
// B-fragment read feeds TWO MFMAs. Per-block LDS traffic 2.56MB -> 1.5MB.
// Math is bit-identical to the 8-wave version (same MFMAs, same rounding).
// 256-thread blocks: 4 waves x 32 q-rows. Double-buffered K/V, XOR-swizzled
// 16B units. O-store goes through the wave-private Ps region for 128B-
// contiguous row stores.
// q,k: bf16 [BH,N,DK] (q pre-scaled); vt: bf16 [BH,DK,N]; out: bf16 [B*N,512].
// ---------------------------------------------------------------------------
__global__ __launch_bounds__(256) void attn_mfma_kernel(
    const short* __restrict__ q, const short* __restrict__ k,
    const short* __restrict__ vt, short* __restrict__ out) {
    const int bh = blockIdx.x;
    const int b = bh >> 3;
    const int h = bh & 7;
    const int n0 = blockIdx.y * 128;
    const int tid = threadIdx.x;
    const int wave = tid >> 6;  // 0..3
    const int lane = tid & 63;
    const int col = lane & 15;
    const int quad = lane >> 4;

    __shared__ short Ks[2][64 * 64];
    __shared__ short Vs[2][64 * 64];
    __shared__ short Ps[4][32][72];

    bf16x8 qa[2][2];
#pragma unroll
    for (int rt = 0; rt < 2; rt++) {
        const size_t qoff =
            ((size_t)bh * NN + n0 + wave * 32 + rt * 16 + col) * DK;
        qa[rt][0] = *(const bf16x8*)&q[qoff + quad * 8];
        qa[rt][1] = *(const bf16x8*)&q[qoff + 32 + quad * 8];
    }

    floatx4 o[2][4];
#pragma unroll
    for (int rt = 0; rt < 2; rt++)
#pragma unroll
        for (int i = 0; i < 4; i++) o[rt][i] = (floatx4){0.f, 0.f, 0.f, 0.f};
    float l_run[2][4] = {{0.f, 0.f, 0.f, 0.f}, {0.f, 0.f, 0.f, 0.f}};

    const short* kg = k + (size_t)bh * NN * DK;
    const short* vg = vt + (size_t)bh * DK * NN;

    const int srow = lane >> 3;
    const int sunit = (lane & 7) ^ srow;
    const int sbase = wave * 16;  // each wave stages 16 rows of K AND V

    const int xs = col & 7;
    const int pK0 = (quad ^ xs) * 8;
    const int pK1 = ((quad + 4) ^ xs) * 8;

#define STAGE(J0, BUF)                                                         \
    do {                                                                       \
        GLD_LDS(kg + (size_t)((J0) + sbase + srow) * DK + sunit * 8,           \
                &Ks[BUF][sbase * 64]);                                         \
        GLD_LDS(kg + (size_t)((J0) + sbase + 8 + srow) * DK + sunit * 8,       \
                &Ks[BUF][(sbase + 8) * 64]);                                   \
        GLD_LDS(vg + (size_t)(sbase + srow) * NN + (J0) + sunit * 8,           \
                &Vs[BUF][sbase * 64]);                                         \
        GLD_LDS(vg + (size_t)(sbase + 8 + srow) * NN + (J0) + sunit * 8,       \
                &Vs[BUF][(sbase + 8) * 64]);                                   \
    } while (0)

    STAGE(0, 0);

    for (int c = 0; c < 16; c++) {
        const int buf = c & 1;
        __syncthreads();
        if (c < 15) STAGE((c + 1) * 64, buf ^ 1);

        const short* K_ = &Ks[buf][0];
        const short* V_ = &Vs[buf][0];

        float p[2][4][4];
#pragma unroll
        for (int ct = 0; ct < 4; ct++) {
            bf16x8 kb0 = *(const bf16x8*)&K_[(ct * 16 + col) * 64 + pK0];
            bf16x8 kb1 = *(const bf16x8*)&K_[(ct * 16 + col) * 64 + pK1];
#pragma unroll
            for (int rt = 0; rt < 2; rt++) {
                floatx4 acc = (floatx4){0.f, 0.f, 0.f, 0.f};
                acc = __builtin_amdgcn_mfma_f32_16x16x32_bf16(qa[rt][0], kb0,
                                                              acc, 0, 0, 0);
                acc = __builtin_amdgcn_mfma_f32_16x16x32_bf16(qa[rt][1], kb1,
                                                              acc, 0, 0, 0);
#pragma unroll
                for (int r = 0; r < 4; r++) p[rt][ct][r] = __expf(acc[r]);
            }
        }

#pragma unroll
        for (int rt = 0; rt < 2; rt++)
#pragma unroll
            for (int r = 0; r < 4; r++)
                l_run[rt][r] +=
                    (p[rt][0][r] + p[rt][1][r]) + (p[rt][2][r] + p[rt][3][r]);

#pragma unroll
        for (int rt = 0; rt < 2; rt++)
#pragma unroll
            for (int ct = 0; ct < 4; ct++)
#pragma unroll
                for (int r = 0; r < 4; r++)
                    Ps[wave][rt * 16 + quad * 4 + r][ct * 16 + col] =
                        f2bf_rhu(p[rt][ct][r]);

        bf16x8 pa[2][2];
#pragma unroll
        for (int rt = 0; rt < 2; rt++) {
            pa[rt][0] = *(const bf16x8*)&Ps[wave][rt * 16 + col][quad * 8];
            pa[rt][1] = *(const bf16x8*)&Ps[wave][rt * 16 + col][32 + quad * 8];
        }

#pragma unroll
        for (int dt = 0; dt < 4; dt++) {
            bf16x8 vb0 = *(const bf16x8*)&V_[(dt * 16 + col) * 64 + pK0];
            bf16x8 vb1 = *(const bf16x8*)&V_[(dt * 16 + col) * 64 + pK1];
#pragma unroll
            for (int rt = 0; rt < 2; rt++) {
                o[rt][dt] = __builtin_amdgcn_mfma_f32_16x16x32_bf16(
                    pa[rt][0], vb0, o[rt][dt], 0, 0, 0);
                o[rt][dt] = __builtin_amdgcn_mfma_f32_16x16x32_bf16(
                    pa[rt][1], vb1, o[rt][dt], 0, 0, 0);
            }
        }
    }
#undef STAGE

    // epilogue: l-reduce, normalize, repack rows through wave-private Ps
    // (wave-internal LDS write->read needs no barrier — same as in-loop P),
    // then 4 lanes/row store 32B each = 128B contiguous per (row, head).
    float inv[2][4];
#pragma unroll
    for (int rt = 0; rt < 2; rt++)
#pragma unroll
        for (int r = 0; r < 4; r++) {
            float lv = l_run[rt][r];
#pragma unroll
            for (int d = 1; d < 16; d <<= 1) lv += __shfl_xor(lv, d, 64);
            inv[rt][r] = 1.f / lv;
        }
#pragma unroll
    for (int rt = 0; rt < 2; rt++)
#pragma unroll
        for (int dt = 0; dt < 4; dt++)
#pragma unroll
            for (int r = 0; r < 4; r++)
                Ps[wave][rt * 16 + quad * 4 + r][dt * 16 + col] =
                    f2bf(o[rt][dt][r] * inv[rt][r]);

#pragma unroll
    for (int rt = 0; rt < 2; rt++) {
        const int row = lane >> 2;       // 0..15
        const int d0 = (lane & 3) * 16;  // 0,16,32,48
        bf16x8 f0 = *(const bf16x8*)&Ps[wave][rt * 16 + row][d0];
        bf16x8 f1 = *(const bf16x8*)&Ps[wave][rt * 16 + row][d0 + 8];
        const int m = n0 + wave * 32 + rt * 16 + row;
        short* orow = out + ((size_t)(b * NN + m)) * 512 + h * 64 + d0;
        *(bf16x8*)&orow[0] = f0;
        *(bf16x8*)&orow[8] = f1;
    }
}

// ---------------------------------------------------------------------------
// Launch (4 kernels — the proven pipeline)
// ---------------------------------------------------------------------------
extern "C" void kernel_launch(void* const* d_in, const int* in_sizes, int n_in,
                              void* d_out, int out_size, void* d_ws,
                              size_t ws_size, hipStream_t stream) {
    const float* x = (const float*)d_in[0];
    const float* Wq = (const float*)d_in[2];
    const float* bq = (const float*)d_in[3];
    const float* Wkv = (const float*)d_in[4];
    const float* bkv = (const float*)d_in[5];
    const float* Wp = (const float*)d_in[6];
    const float* bp = (const float*)d_in[7];
    float* out = (float*)d_out;

    short* ws = (short*)d_ws;
    short* xtb = ws;                                  // [8192, 512]  8 MB
    short* qb = xtb + (size_t)MROWS * CC;             // [64,1024,64] 8 MB
    short* kb = qb + (size_t)MROWS * INNER;           // [64,1024,64] 8 MB
    short* vb = kb + (size_t)MROWS * INNER;           // [64,64,1024] 8 MB (T)
    short* wqkvb = vb + (size_t)MROWS * INNER;        // [1536,512] 1.5 MB
    short* wpb = wqkvb + (size_t)3 * INNER * CC;      // [512,512]  0.5 MB
    float* bqkv = (float*)(wpb + (size_t)CC * INNER); // [1536] fp32
    short* att = xtb;  // reuse: attention reads only q/k/vt

    prep_kernel<<<4096 + 1026, 256, 0, stream>>>(x, Wq, Wkv, Wp, bq, bkv, xtb,
                                                 wqkvb, wpb, bqkv);
    {
        dim3 grid(MROWS / 128, (3 * INNER) / 128);
        gemm_mfma_kernel<1, 128><<<grid, 256, 0, stream>>>(
            xtb, wqkvb, bqkv, nullptr, qb, kb, vb);
    }
    {
        dim3 grid(BB * NH, NN / 128);
        attn_mfma_kernel<<<grid, 256, 0, stream>>>(qb, kb, vb, att);
    }
    {
        dim3 grid(MROWS / 128, CC / 64);
        gemm_mfma_kernel<0, 64><<<grid, 256, 0, stream>>>(
            att, wpb, bp, out, nullptr, nullptr, nullptr);
    }
}

// Round 2
// 144.998 us; speedup vs baseline: 1.0489x; 1.0489x over previous
//
#include <hip/hip_runtime.h>
#include <math.h>

// Problem constants (fixed by reference)
#define BB 8
#define CC 512
#define NH 8
#define DK 64
#define NN 1024          // Hs*Ws = 32*32
#define MROWS (BB * NN)  // 8192
#define INNER 512        // NH*DK
// R14: Q pre-scale now folds log2(e) so attention uses native exp2:
//   exp(S) = exp2(S * log2e), with log2e folded into Q before bf16 rounding.
#define QSCALE 0.18033688011112042f  // 0.125 * log2(e)

// NOTE (R8-R11 lesson): single-kernel fusion via grid-wide barriers is dead on
// this harness. cg::grid().sync computes correctly (R9 direct call) but
// hipLaunchCooperativeKernel breaks graph capture; hand-rolled barriers with
// __threadfence / __threadfence_system both leave stale per-XCD L2 lines
// (R10: 1.71e-2, R11: 1.67e-2 partial corruption). 4-kernel pipeline it is.

typedef __attribute__((ext_vector_type(8))) short bf16x8;
typedef __attribute__((ext_vector_type(4))) float floatx4;
typedef __attribute__((ext_vector_type(16))) float floatx16;

__device__ inline short f2bf(float f) {  // RNE
    union { float f; unsigned u; } un;
    un.f = f;
    unsigned r = un.u + 0x7fffu + ((un.u >> 16) & 1u);
    return (short)(r >> 16);
}

#if defined(__has_builtin)
#if __has_builtin(__builtin_amdgcn_exp2f)
#define EXP2(x) __builtin_amdgcn_exp2f(x)
#else
#define EXP2(x) __expf((x) * 0.69314718056f)
#endif
#else
#define EXP2(x) __expf((x) * 0.69314718056f)
#endif

#define GLD_LDS(gptr, lptr)                                                  \
    __builtin_amdgcn_global_load_lds(                                        \
        (const __attribute__((address_space(1))) void*)(gptr),               \
        (__attribute__((address_space(3))) void*)(lptr), 16, 0, 0)

// ---------------------------------------------------------------------------
// Kernel 1: fused prep — transpose x [B,C,N]->[B,N,C] bf16 (blocks 0..4095),
// weight cvt Wq|Wkv -> wqkvb [1536][512], Wp -> wpb, bias concat (>=4096).
// ---------------------------------------------------------------------------
__global__ __launch_bounds__(256) void prep_kernel(
    const float* __restrict__ x, const float* __restrict__ Wq,
    const float* __restrict__ Wkv, const float* __restrict__ Wp,
    const float* __restrict__ bq, const float* __restrict__ bkv,
    short* __restrict__ xtb, short* __restrict__ wqkvb,
    short* __restrict__ wpb, float* __restrict__ bqkv) {
    __shared__ float tile[32][33];
    const int bid = blockIdx.x;
    if (bid < 4096) {
        const int n0 = (bid & 31) * 32;
        const int c0 = ((bid >> 5) & 15) * 32;
        const int b = bid >> 9;
        const int tx = threadIdx.x & 31;
        const int ty = threadIdx.x >> 5;
        const float* xb = x + (size_t)b * CC * NN;
        short* xo = xtb + (size_t)b * NN * CC;
        for (int i = ty; i < 32; i += 8)
            tile[i][tx] = xb[(size_t)(c0 + i) * NN + n0 + tx];
        __syncthreads();
        for (int i = ty; i < 32; i += 8)
            xo[(size_t)(n0 + i) * CC + c0 + tx] = f2bf(tile[tx][i]);
    } else {
        const int i = (bid - 4096) * 1024 + threadIdx.x * 4;
        if (i < 786432) {
            float4 v = (i < 262144) ? *(const float4*)&Wq[i]
                                    : *(const float4*)&Wkv[i - 262144];
            wqkvb[i + 0] = f2bf(v.x);
            wqkvb[i + 1] = f2bf(v.y);
            wqkvb[i + 2] = f2bf(v.z);
            wqkvb[i + 3] = f2bf(v.w);
        } else if (i < 1048576) {
            const int j = i - 786432;
            float4 v = *(const float4*)&Wp[j];
            wpb[j + 0] = f2bf(v.x);
            wpb[j + 1] = f2bf(v.y);
            wpb[j + 2] = f2bf(v.z);
            wpb[j + 3] = f2bf(v.w);
        } else {
            const int j = i - 1048576;
            if (j < 1536) {
                float4 v = (j < 512) ? *(const float4*)&bq[j]
                                     : *(const float4*)&bkv[j - 512];
                *(float4*)&bqkv[j] = v;
            }
        }
    }
}

// ---------------------------------------------------------------------------
// Kernel 2: bf16 MFMA GEMM  out = A @ W^T + bias
//   128 x BN tile, BK=32, 256 thr (4 waves), double-buffered K-loop.
//   MODE 0: fp32 row-major to outf (final projection, Nw=512)
//   MODE 1: fused QKV (Nw=1536). ALL outputs go through an LDS C-repack for
//     fully-coalesced stores (R7 proved V; R12 extends to Q/K):
//       V  (bn0>=1024): Cs[jn][m] -> vt rows, 16B frags along n (256B spans)
//       Q/K (bn0<1024): Cs[m][jn] -> q/k rows, 16B frags along d (128B spans)
//   Q epilogue multiplies by QSCALE (attention scale * log2e, see R14).
// ---------------------------------------------------------------------------
template <int MODE, int BN>
__global__ __launch_bounds__(256) void gemm_mfma_kernel(
    const short* __restrict__ A, const short* __restrict__ W,
    const float* __restrict__ bias, float* __restrict__ outf,
    short* __restrict__ outq, short* __restrict__ outk,
    short* __restrict__ outv) {
    constexpr int K = 512;
    constexpr int WCOLS = BN / 64;
    constexpr int WROWS = 4 / WCOLS;
    constexpr int WRSPAN = 128 / WROWS;
    constexpr int RT = WRSPAN / 16;
    constexpr int ABUF = 128 * 32;
    constexpr int BBUF = BN * 32;
    constexpr int STAGE_EL = 2 * ABUF + 2 * BBUF;
    constexpr int CS_EL = (MODE == 1) ? 128 * 132 : 0;  // repack tile
    constexpr int SMEM_EL = (CS_EL > STAGE_EL) ? CS_EL : STAGE_EL;
    __shared__ short smem[SMEM_EL];
    short* As = smem;
    short* Bs = smem + 2 * ABUF;

    const int t = threadIdx.x;
    const int wave = t >> 6;
    const int lane = t & 63;
    const int col = lane & 15;
    const int quad = lane >> 4;
    const int wr = wave / WCOLS;
    const int wc = wave % WCOLS;

    const int bm0 = blockIdx.x * 128;
    const int bn0 = blockIdx.y * BN;

    floatx4 acc[RT][4];
#pragma unroll
    for (int i = 0; i < RT; i++)
#pragma unroll
        for (int j = 0; j < 4; j++) acc[i][j] = (floatx4){0.f, 0.f, 0.f, 0.f};

    const int kpE = (lane & 3) * 8;
    const int rA = wave * 32 + (lane >> 2);
    const short* Ag = A + (size_t)(bm0 + rA) * K + kpE;
    const int rB = wave * (BN / 4) + (lane >> 2);
    const short* Wg = W + (size_t)(bn0 + rB) * K + kpE;
    const int aOff = wave * 1024;
    const int bOff = wave * (BN / 4) * 32;

#define GSTAGE(K0, BUF)                                                       \
    do {                                                                      \
        GLD_LDS(Ag + (K0), As + (BUF)*ABUF + aOff);                           \
        GLD_LDS(Ag + 16 * K + (K0), As + (BUF)*ABUF + aOff + 512);            \
        if constexpr (BN == 128) {                                            \
            GLD_LDS(Wg + (K0), Bs + (BUF)*BBUF + bOff);                       \
            GLD_LDS(Wg + 16 * K + (K0), Bs + (BUF)*BBUF + bOff + 512);        \
        } else {                                                              \
            GLD_LDS(Wg + (K0), Bs + (BUF)*BBUF + bOff);                       \
        }                                                                     \
    } while (0)

    GSTAGE(0, 0);

#pragma unroll
    for (int it = 0; it < 16; it++) {
        const int buf = it & 1;
        __syncthreads();
        if (it < 15) GSTAGE((it + 1) * 32, buf ^ 1);

        const short* A_ = As + buf * ABUF;
        const short* B_ = Bs + buf * BBUF;
        bf16x8 aF[RT], bF[4];
#pragma unroll
        for (int rt = 0; rt < RT; rt++)
            aF[rt] =
                *(const bf16x8*)&A_[(wr * WRSPAN + rt * 16 + col) * 32 + quad * 8];
#pragma unroll
        for (int ct = 0; ct < 4; ct++)
            bF[ct] = *(const bf16x8*)&B_[(wc * 64 + ct * 16 + col) * 32 + quad * 8];
#pragma unroll
        for (int rt = 0; rt < RT; rt++)
#pragma unroll
            for (int ct = 0; ct < 4; ct++)
                acc[rt][ct] = __builtin_amdgcn_mfma_f32_16x16x32_bf16(
                    aF[rt], bF[ct], acc[rt][ct], 0, 0, 0);
    }
#undef GSTAGE

    if (MODE == 1) {
        short* Cs = smem;  // reuses staging area; stride 132 breaks pow-2 banks
        const bool isV = (bn0 >= 1024);
        const bool isQ = (bn0 < 512);
        __syncthreads();  // all waves done reading As/Bs
        if (isV) {
            // V: Cs[jn][m], short4 along m (values identical to R8 path)
#pragma unroll
            for (int rt = 0; rt < RT; rt++) {
#pragma unroll
                for (int ct = 0; ct < 4; ct++) {
                    const int jn_l = wc * 64 + ct * 16 + col;
                    const float bsv = bias[bn0 + jn_l];
                    const int m_l = wr * WRSPAN + rt * 16 + quad * 4;
                    short4 v4;
                    v4.x = f2bf(acc[rt][ct][0] + bsv);
                    v4.y = f2bf(acc[rt][ct][1] + bsv);
                    v4.z = f2bf(acc[rt][ct][2] + bsv);
                    v4.w = f2bf(acc[rt][ct][3] + bsv);
                    *(short4*)&Cs[jn_l * 132 + m_l] = v4;
                }
            }
        } else {
            // Q/K: Cs[m][jn] (jn contiguous -> 16B frags along d at store)
#pragma unroll
            for (int rt = 0; rt < RT; rt++) {
#pragma unroll
                for (int ct = 0; ct < 4; ct++) {
                    const int jn_l = wc * 64 + ct * 16 + col;
                    const float bsv = bias[bn0 + jn_l];
#pragma unroll
                    for (int r = 0; r < 4; r++) {
                        const int m_l = wr * WRSPAN + rt * 16 + quad * 4 + r;
                        const float val = acc[rt][ct][r] + bsv;
                        Cs[m_l * 132 + jn_l] =
                            isQ ? f2bf(val * QSCALE) : f2bf(val);
                    }
                }
            }
        }
        __syncthreads();
        const int b = bm0 >> 10;
        const int nbase = bm0 & 1023;
        if (isV) {
#pragma unroll
            for (int p = 0; p < 8; p++) {
                const int cid = p * 256 + t;
                const int jn_l = cid >> 4;
                const int m0 = (cid & 15) * 8;
                bf16x8 frag = *(const bf16x8*)&Cs[jn_l * 132 + m0];
                const int jn_g = bn0 + jn_l;
                const int h = (jn_g >> 6) & 7;
                const int d = jn_g & 63;
                *(bf16x8*)&outv[(((size_t)(b * NH + h)) * DK + d) * NN + nbase +
                                m0] = frag;
            }
        } else {
            short* dst = isQ ? outq : outk;
#pragma unroll
            for (int p = 0; p < 8; p++) {
                const int cid = p * 256 + t;
                const int m_l = cid >> 4;
                const int jn0 = (cid & 15) * 8;
                bf16x8 frag = *(const bf16x8*)&Cs[m_l * 132 + jn0];
                const int jn_g = bn0 + jn0;
                const int h = (jn_g >> 6) & 7;
                const int d = jn_g & 63;
                *(bf16x8*)&dst[(((size_t)(b * NH + h)) * NN + nbase + m_l) * DK +
                               d] = frag;
            }
        }
        return;
    }

    // MODE 0: fp32 row-major store (already coalesced per 16-lane col group)
#pragma unroll
    for (int rt = 0; rt < RT; rt++) {
#pragma unroll
        for (int ct = 0; ct < 4; ct++) {
            const int jn = bn0 + wc * 64 + ct * 16 + col;
            const float bsv = bias[jn];
#pragma unroll
            for (int r = 0; r < 4; r++) {
                const int m = bm0 + wr * WRSPAN + rt * 16 + quad * 4 + r;
                outf[(size_t)m * 512 + jn] = acc[rt][ct][r] + bsv;
            }
        }
    }
}

// ---------------------------------------------------------------------------
// Kernel 3: MFMA flash attention, bf16 (no online max: scores bounded ~1.3).
// R14: softmax fully in-register via swapped QK^T (T12 / m214 recipe):
//   - S^T = mfma_32x32x16(K, Q): lane owns P[q=lane&31][k=(reg&3)+8(reg>>2)
//     +4*(lane>>5)] -> exp2 in-reg (log2e pre-folded into Q by the GEMM).
//   - P->bf16 via v_cvt_pk_bf16_f32 (16 ops), PV A-frags assembled with
//     v_permlane32_swap_b32 (8 ops). NO P LDS round-trip (was 32 ds_write_b16
//     + 4 ds_read_b128 per wave-iter); Ps buffer deleted (LDS 50->32 KB).
//   - PV: O[q][d] = mfma_32x32x16(PA, Vt-frag); O lanes hold d=lane&31,
//     q from regs; epilogue gathers 1/l via 16 shfl, stores bf16 scalars
//     (half-wave writes are 64B-contiguous runs).
// 4 waves x 32 q-rows, double-buffered K/V, XOR-swizzled 16B units.
// q,k: bf16 [BH,N,DK] (q pre-scaled by QSCALE); vt: bf16 [BH,DK,N];
// out: bf16 [B*N,512].
// ---------------------------------------------------------------------------
__global__ __launch_bounds__(256) void attn_mfma_kernel(
    const short* __restrict__ q, const short* __restrict__ k,
    const short* __restrict__ vt, short* __restrict__ out) {
    const int bh = blockIdx.x;
    const int b = bh >> 3;
    const int h = bh & 7;
    const int n0 = blockIdx.y * 128;
    const int tid = threadIdx.x;
    const int wave = tid >> 6;  // 0..3
    const int lane = tid & 63;
    const int l31 = lane & 31;
    const int hi = lane >> 5;
    const int rsw = l31 & 7;

    __shared__ short Ks[2][64 * 64];
    __shared__ short Vs[2][64 * 64];

    // Q B-frags: col=l31 (q-row), contraction d = dc*16 + hi*8 + e
    bf16x8 qf[4];
    {
        const size_t qbase =
            ((size_t)bh * NN + n0 + wave * 32 + l31) * DK + hi * 8;
#pragma unroll
        for (int dc = 0; dc < 4; dc++)
            qf[dc] = *(const bf16x8*)&q[qbase + dc * 16];
    }

    floatx16 o[2];
#pragma unroll
    for (int dt = 0; dt < 2; dt++)
#pragma unroll
        for (int i = 0; i < 16; i++) o[dt][i] = 0.f;
    float l_run = 0.f;

    const short* kg = k + (size_t)bh * NN * DK;
    const short* vg = vt + (size_t)bh * DK * NN;

    const int srow = lane >> 3;
    const int sunit = (lane & 7) ^ srow;
    const int sbase = wave * 16;  // each wave stages 16 rows of K AND V

#define STAGE(J0, BUF)                                                         \
    do {                                                                       \
        GLD_LDS(kg + (size_t)((J0) + sbase + srow) * DK + sunit * 8,           \
                &Ks[BUF][sbase * 64]);                                         \
        GLD_LDS(kg + (size_t)((J0) + sbase + 8 + srow) * DK + sunit * 8,       \
                &Ks[BUF][(sbase + 8) * 64]);                                   \
        GLD_LDS(vg + (size_t)(sbase + srow) * NN + (J0) + sunit * 8,           \
                &Vs[BUF][sbase * 64]);                                         \
        GLD_LDS(vg + (size_t)(sbase + 8 + srow) * NN + (J0) + sunit * 8,       \
                &Vs[BUF][(sbase + 8) * 64]);                                   \
    } while (0)

    STAGE(0, 0);

    for (int c = 0; c < 16; c++) {
        const int buf = c & 1;
        __syncthreads();
        if (c < 15) STAGE((c + 1) * 64, buf ^ 1);

        const short* K_ = &Ks[buf][0];
        const short* V_ = &Vs[buf][0];

        // ---- QK^T (swapped): sacc[kt] holds S^T; lane: q=l31,
        //      k = kt*32 + 4*hi + (reg&3) + 8*(reg>>2)
        floatx16 sacc[2];
#pragma unroll
        for (int kt = 0; kt < 2; kt++) {
#pragma unroll
            for (int i = 0; i < 16; i++) sacc[kt][i] = 0.f;
#pragma unroll
            for (int dc = 0; dc < 4; dc++) {
                bf16x8 kf = *(const bf16x8*)&K_[(kt * 32 + l31) * 64 +
                                                (((dc * 2 + hi) ^ rsw) * 8)];
                sacc[kt] = __builtin_amdgcn_mfma_f32_32x32x16_bf16(
                    kf, qf[dc], sacc[kt], 0, 0, 0);
            }
        }

        // ---- exp2 + pack + cross-half swap -> PV A-fragments in registers
        unsigned pw[2][4][2];  // [kt][s][j]: bf16 pair, kp_loc = 2*hi + j + 4*s
#pragma unroll
        for (int kt = 0; kt < 2; kt++) {
            float p[16];
#pragma unroll
            for (int i = 0; i < 16; i++) p[i] = EXP2(sacc[kt][i]);
            // pairwise tree sum (shallow dep chain)
            float s0 = (p[0] + p[1]) + (p[2] + p[3]);
            float s1 = (p[4] + p[5]) + (p[6] + p[7]);
            float s2 = (p[8] + p[9]) + (p[10] + p[11]);
            float s3 = (p[12] + p[13]) + (p[14] + p[15]);
            l_run += (s0 + s1) + (s2 + s3);
#pragma unroll
            for (int s = 0; s < 4; s++)
#pragma unroll
                for (int j = 0; j < 2; j++)
                    asm("v_cvt_pk_bf16_f32 %0, %1, %2"
                        : "=v"(pw[kt][s][j])
                        : "v"(p[4 * s + 2 * j]), "v"(p[4 * s + 2 * j + 1]));
#pragma unroll
            for (int cc = 0; cc < 2; cc++)
#pragma unroll
                for (int j = 0; j < 2; j++)
                    asm("v_permlane32_swap_b32 %0, %1"
                        : "+v"(pw[kt][2 * cc][j]), "+v"(pw[kt][2 * cc + 1][j]));
        }
        // assemble PA[kc]: kc = 2*kt + cc covers k_loc [kc*16, kc*16+16)
        bf16x8 PA[4];
#pragma unroll
        for (int kc = 0; kc < 4; kc++) {
            const int kt = kc >> 1, cc = kc & 1;
            union { unsigned w[4]; bf16x8 v; } pa;
            pa.w[0] = pw[kt][2 * cc][0];
            pa.w[1] = pw[kt][2 * cc][1];
            pa.w[2] = pw[kt][2 * cc + 1][0];
            pa.w[3] = pw[kt][2 * cc + 1][1];
            PA[kc] = pa.v;
        }

        // ---- PV: O[q][d] += P[q][k] * Vt[d][k]
#pragma unroll
        for (int dt = 0; dt < 2; dt++)
#pragma unroll
            for (int kc = 0; kc < 4; kc++) {
                bf16x8 vf = *(const bf16x8*)&V_[(dt * 32 + l31) * 64 +
                                                (((kc * 2 + hi) ^ rsw) * 8)];
                o[dt] = __builtin_amdgcn_mfma_f32_32x32x16_bf16(PA[kc], vf,
                                                                o[dt], 0, 0, 0);
            }
    }
#undef STAGE

    // ---- epilogue: combine half-wave l partials, gather 1/l per q, store.
    l_run += __shfl_xor(l_run, 32, 64);
    const float inv = 1.f / l_run;  // valid for q = l31 (both halves)
    float invq[4][4];
#pragma unroll
    for (int s = 0; s < 4; s++)
#pragma unroll
        for (int rr = 0; rr < 4; rr++)
            invq[s][rr] = __shfl(inv, 4 * hi + rr + 8 * s, 64);

#pragma unroll
    for (int dt = 0; dt < 2; dt++)
#pragma unroll
        for (int s = 0; s < 4; s++)
#pragma unroll
            for (int rr = 0; rr < 4; rr++) {
                const int qloc = 4 * hi + rr + 8 * s;
                const int m = n0 + wave * 32 + qloc;
                out[((size_t)(b * NN + m)) * 512 + h * 64 + dt * 32 + l31] =
                    f2bf(o[dt][4 * s + rr] * invq[s][rr]);
            }
}

// ---------------------------------------------------------------------------
// Launch (4 kernels — the proven pipeline)
// ---------------------------------------------------------------------------
extern "C" void kernel_launch(void* const* d_in, const int* in_sizes, int n_in,
                              void* d_out, int out_size, void* d_ws,
                              size_t ws_size, hipStream_t stream) {
    const float* x = (const float*)d_in[0];
    const float* Wq = (const float*)d_in[2];
    const float* bq = (const float*)d_in[3];
    const float* Wkv = (const float*)d_in[4];
    const float* bkv = (const float*)d_in[5];
    const float* Wp = (const float*)d_in[6];
    const float* bp = (const float*)d_in[7];
    float* out = (float*)d_out;

    short* ws = (short*)d_ws;
    short* xtb = ws;                                  // [8192, 512]  8 MB
    short* qb = xtb + (size_t)MROWS * CC;             // [64,1024,64] 8 MB
    short* kb = qb + (size_t)MROWS * INNER;           // [64,1024,64] 8 MB
    short* vb = kb + (size_t)MROWS * INNER;           // [64,64,1024] 8 MB (T)
    short* wqkvb = vb + (size_t)MROWS * INNER;        // [1536,512] 1.5 MB
    short* wpb = wqkvb + (size_t)3 * INNER * CC;      // [512,512]  0.5 MB
    float* bqkv = (float*)(wpb + (size_t)CC * INNER); // [1536] fp32
    short* att = xtb;  // reuse: attention reads only q/k/vt

    prep_kernel<<<4096 + 1026, 256, 0, stream>>>(x, Wq, Wkv, Wp, bq, bkv, xtb,
                                                 wqkvb, wpb, bqkv);
    {
        dim3 grid(MROWS / 128, (3 * INNER) / 128);
        gemm_mfma_kernel<1, 128><<<grid, 256, 0, stream>>>(
            xtb, wqkvb, bqkv, nullptr, qb, kb, vb);
    }
    {
        dim3 grid(BB * NH, NN / 128);
        attn_mfma_kernel<<<grid, 256, 0, stream>>>(qb, kb, vb, att);
    }
    {
        dim3 grid(MROWS / 128, CC / 64);
        gemm_mfma_kernel<0, 64><<<grid, 256, 0, stream>>>(
            att, wpb, bp, out, nullptr, nullptr, nullptr);
    }
}